// Round 4
// baseline (542.402 us; speedup 1.0000x reference)
//
#include <hip/hip_runtime.h>
#include <math.h>

#define B_   4
#define H_   48
#define W_   48
#define DM_  192
#define DI_  384
#define L_   2304      // H_*W_
#define K_   4
#define DS_  16
#define DTR_ 12
#define C44  44        // DTR + 2*DS

// scan chunking
#define NC   64
#define CL   36                        // L_/NC
#define NSER (B_*K_*DI_*DS_)           // 98304 series (b,k,d,n)

// ---------------------------------------------------------------------------
// Generic batched NT GEMM: C[m,n] = sum_k A[m,k]*B[n,k]
// ---------------------------------------------------------------------------
#define BM 64
#define BN 64
#define BKT 16

template<int EPI>
__global__ __launch_bounds__(256) void gemm_nt(
    const float* __restrict__ Ag, const float* __restrict__ Bg,
    float* __restrict__ Cg, const float* __restrict__ biasg,
    int M, int N, int Kd, int lda, int ldb, int ldc,
    long sA, long sB, int bmod, long sC)
{
    const int batch = blockIdx.z;
    const float* A = Ag + (long)batch * sA;
    const float* Bm = Bg + (long)(batch % bmod) * sB;
    float* C = Cg + (long)batch * sC;
    const float* bias = (EPI == 1) ? (biasg + (long)(batch % bmod) * N) : nullptr;

    __shared__ float As[BKT][BM + 4];
    __shared__ float Bs[BKT][BN + 4];

    const int tid = threadIdx.x;
    const int tx = tid & 15;
    const int ty = tid >> 4;
    const int row0 = blockIdx.x * BM;
    const int col0 = blockIdx.y * BN;

    const int kc = tid & (BKT - 1);
    const int rr = tid >> 4;

    float acc[4][4] = {};

    for (int k0 = 0; k0 < Kd; k0 += BKT) {
        #pragma unroll
        for (int p = 0; p < 4; ++p) {
            int r = rr + p * 16;
            int gk = k0 + kc;
            int gr = row0 + r;
            float va = 0.f;
            if (gr < M && gk < Kd) va = A[(long)gr * lda + gk];
            As[kc][r] = va;
            int gc = col0 + r;
            float vb = 0.f;
            if (gc < N && gk < Kd) vb = Bm[(long)gc * ldb + gk];
            Bs[kc][r] = vb;
        }
        __syncthreads();
        #pragma unroll
        for (int kk = 0; kk < BKT; ++kk) {
            float a[4], b[4];
            #pragma unroll
            for (int i = 0; i < 4; ++i) a[i] = As[kk][ty * 4 + i];
            #pragma unroll
            for (int j = 0; j < 4; ++j) b[j] = Bs[kk][tx * 4 + j];
            #pragma unroll
            for (int i = 0; i < 4; ++i)
                #pragma unroll
                for (int j = 0; j < 4; ++j)
                    acc[i][j] += a[i] * b[j];
        }
        __syncthreads();
    }

    #pragma unroll
    for (int i = 0; i < 4; ++i) {
        int gr = row0 + ty * 4 + i;
        if (gr >= M) continue;
        #pragma unroll
        for (int j = 0; j < 4; ++j) {
            int gc = col0 + tx * 4 + j;
            if (gc >= N) continue;
            float v = acc[i][j];
            if (EPI == 1) {
                v += bias[gc];
                v = (v > 20.f) ? v : log1pf(__expf(v));
            }
            C[(long)gr * ldc + gc] = v;
        }
    }
}

// ---------------------------------------------------------------------------
// Depthwise/grouped 3x3 convs + bias + SiLU.
// ---------------------------------------------------------------------------
__global__ __launch_bounds__(256) void conv_dw(
    const float* __restrict__ xz, const float* __restrict__ xt,
    const float* __restrict__ w1, const float* __restrict__ b1,
    const float* __restrict__ w2, const float* __restrict__ b2,
    float* __restrict__ xc, float* __restrict__ xtc)
{
    const int total = B_ * H_ * W_ * DI_;
    int idx = blockIdx.x * blockDim.x + threadIdx.x;
    if (idx >= 2 * total) return;
    const bool second = idx >= total;
    int i = second ? idx - total : idx;
    const int c = i % DI_;
    int rest = i / DI_;
    const int w = rest % W_; rest /= W_;
    const int h = rest % H_;
    const int b = rest / H_;

    float acc;
    if (!second) {
        acc = b1[c];
        const float* wp = w1 + c * 9;
        #pragma unroll
        for (int dh = 0; dh < 3; ++dh) {
            int hh = h + dh - 1;
            if (hh < 0 || hh >= H_) continue;
            #pragma unroll
            for (int dw = 0; dw < 3; ++dw) {
                int ww = w + dw - 1;
                if (ww < 0 || ww >= W_) continue;
                acc += xz[((long)((b * H_ + hh) * W_ + ww)) * (2 * DI_) + c] * wp[dh * 3 + dw];
            }
        }
    } else {
        acc = b2[c];
        const int ci = c >> 1;
        const float* wp = w2 + c * 9;
        #pragma unroll
        for (int dh = 0; dh < 3; ++dh) {
            int hh = h + dh - 1;
            if (hh < 0 || hh >= H_) continue;
            #pragma unroll
            for (int dw = 0; dw < 3; ++dw) {
                int ww = w + dw - 1;
                if (ww < 0 || ww >= W_) continue;
                acc += xt[((long)((b * H_ + hh) * W_ + ww)) * DM_ + ci] * wp[dh * 3 + dw];
            }
        }
    }
    float v = acc / (1.f + __expf(-acc));   // SiLU
    (second ? xtc : xc)[i] = v;
}

// ---------------------------------------------------------------------------
// Build xs[B,4,L,DI]
// ---------------------------------------------------------------------------
__global__ __launch_bounds__(256) void build_xs(
    const float* __restrict__ xc, const float* __restrict__ xtc,
    float* __restrict__ xs)
{
    const int total = B_ * H_ * W_ * DI_;
    int idx = blockIdx.x * blockDim.x + threadIdx.x;
    if (idx >= total) return;
    const int d = idx % DI_;
    int rest = idx / DI_;
    const int w = rest % W_; rest /= W_;
    const int h = rest % H_;
    const int b = rest / H_;

    float a, bb, ir, ic;
    if ((h & 1) == 0) {
        a  = xc[((long)((b * H_ + h)     * W_ + w)) * DI_ + d];
        bb = xc[((long)((b * H_ + h + 1) * W_ + w)) * DI_ + d];
    } else {
        a  = xtc[((long)((b * H_ + h - 1) * W_ + w)) * DI_ + d];
        bb = xtc[((long)((b * H_ + h)     * W_ + w)) * DI_ + d];
    }
    ir = 0.5f * (a + bb) + fmaxf(a, bb);
    if ((w & 1) == 0) {
        a  = xc[((long)((b * H_ + h) * W_ + w))     * DI_ + d];
        bb = xc[((long)((b * H_ + h) * W_ + w + 1)) * DI_ + d];
    } else {
        a  = xtc[((long)((b * H_ + h) * W_ + w - 1)) * DI_ + d];
        bb = xtc[((long)((b * H_ + h) * W_ + w))     * DI_ + d];
    }
    ic = 0.5f * (a + bb) + fmaxf(a, bb);

    long base = (long)b * K_ * L_ * DI_;
    xs[base + 0L * L_ * DI_ + (long)(w * H_ + h)            * DI_ + d] = ir;
    xs[base + 1L * L_ * DI_ + (long)(w * H_ + (H_ - 1 - h)) * DI_ + d] = ir;
    xs[base + 2L * L_ * DI_ + (long)(h * W_ + w)            * DI_ + d] = ic;
    xs[base + 3L * L_ * DI_ + (long)(h * W_ + (W_ - 1 - w)) * DI_ + d] = ic;
}

// ---------------------------------------------------------------------------
// Chunked selective scan, 3 passes, with the dt-projection + softplus FUSED
// (delta never materialized). One thread per d-channel, 16 states in VGPRs.
// Block = 384 threads = one (b,k,chunk). Carry layout: [chunk][(bk*DI+d)*16+n].
// ---------------------------------------------------------------------------
__device__ __forceinline__ float fused_delta(
    const float* __restrict__ rb, const float wt[12], float bias)
{
    float4 t0 = ((const float4*)rb)[0];
    float4 t1 = ((const float4*)rb)[1];
    float4 t2 = ((const float4*)rb)[2];
    float v = bias;
    v += t0.x * wt[0] + t0.y * wt[1] + t0.z * wt[2] + t0.w * wt[3];
    v += t1.x * wt[4] + t1.y * wt[5] + t1.z * wt[6] + t1.w * wt[7];
    v += t2.x * wt[8] + t2.y * wt[9] + t2.z * wt[10] + t2.w * wt[11];
    return (v > 20.f) ? v : log1pf(__expf(v));
}

__global__ __launch_bounds__(384) void scan_p1(
    const float* __restrict__ xs, const float* __restrict__ xdbl,
    const float* __restrict__ A_logs, const float* __restrict__ dtw,
    const float* __restrict__ dtb,
    float* __restrict__ carryS, float* __restrict__ carryP)
{
    const int chunk = blockIdx.x % (NC - 1);
    const int bk = blockIdx.x / (NC - 1);
    const int k = bk % K_;
    const int d = threadIdx.x;

    float An[16];
    #pragma unroll
    for (int n = 0; n < 16; ++n)
        An[n] = -__expf(A_logs[(long)(k * DI_ + d) * DS_ + n]);

    float wt[12];
    {
        const float* wp = dtw + ((long)k * DI_ + d) * DTR_;
        *(float4*)&wt[0] = ((const float4*)wp)[0];
        *(float4*)&wt[4] = ((const float4*)wp)[1];
        *(float4*)&wt[8] = ((const float4*)wp)[2];
    }
    const float bias = dtb[k * DI_ + d];

    const long l0 = (long)chunk * CL;
    const float* xsp = xs + (long)bk * L_ * DI_ + l0 * DI_ + d;
    const float* rbase = xdbl + (long)bk * L_ * C44 + l0 * C44;

    float s[16];
    #pragma unroll
    for (int n = 0; n < 16; ++n) s[n] = 0.f;
    float sdl = 0.f;

    for (int l = 0; l < CL; ++l) {
        const float* rb = rbase + (long)l * C44;
        float u = xsp[(long)l * DI_];
        float dl = fused_delta(rb, wt, bias);
        float B[16];
        *(float4*)&B[0]  = ((const float4*)rb)[3];
        *(float4*)&B[4]  = ((const float4*)rb)[4];
        *(float4*)&B[8]  = ((const float4*)rb)[5];
        *(float4*)&B[12] = ((const float4*)rb)[6];
        const float du = dl * u;
        sdl += dl;
        #pragma unroll
        for (int n = 0; n < 16; ++n)
            s[n] = s[n] * __expf(dl * An[n]) + du * B[n];
    }

    const long sidb = ((long)bk * DI_ + d) * 16;
    float* cs = carryS + (long)chunk * NSER + sidb;
    float* cpp = carryP + (long)chunk * NSER + sidb;
    #pragma unroll
    for (int q = 0; q < 4; ++q) {
        float4 v; v.x = s[q*4]; v.y = s[q*4+1]; v.z = s[q*4+2]; v.w = s[q*4+3];
        ((float4*)cs)[q] = v;
        float4 p;
        p.x = __expf(An[q*4+0] * sdl); p.y = __expf(An[q*4+1] * sdl);
        p.z = __expf(An[q*4+2] * sdl); p.w = __expf(An[q*4+3] * sdl);
        ((float4*)cpp)[q] = p;
    }
}

// sequential combine across chunks, in place: after this, carryS[c-1] holds
// the incoming state for chunk c (chunk 0 incoming = 0).
__global__ __launch_bounds__(256) void scan_p2(
    float* __restrict__ carryS, const float* __restrict__ carryP)
{
    const int sid = blockIdx.x * 256 + threadIdx.x;
    float s = 0.f;
    #pragma unroll
    for (int c = 1; c < NC; ++c) {
        float Sv = carryS[(long)(c - 1) * NSER + sid];
        float Pv = carryP[(long)(c - 1) * NSER + sid];
        s = Pv * s + Sv;
        carryS[(long)(c - 1) * NSER + sid] = s;
    }
}

__global__ __launch_bounds__(384) void scan_p3(
    const float* __restrict__ xs, const float* __restrict__ xdbl,
    const float* __restrict__ A_logs, const float* __restrict__ dtw,
    const float* __restrict__ dtb, const float* __restrict__ Ds,
    const float* __restrict__ carryS, float* __restrict__ outy)
{
    const int chunk = blockIdx.x % NC;
    const int bk = blockIdx.x / NC;
    const int k = bk % K_;
    const int d = threadIdx.x;

    float An[16];
    #pragma unroll
    for (int n = 0; n < 16; ++n)
        An[n] = -__expf(A_logs[(long)(k * DI_ + d) * DS_ + n]);
    const float Dv = Ds[k * DI_ + d];

    float wt[12];
    {
        const float* wp = dtw + ((long)k * DI_ + d) * DTR_;
        *(float4*)&wt[0] = ((const float4*)wp)[0];
        *(float4*)&wt[4] = ((const float4*)wp)[1];
        *(float4*)&wt[8] = ((const float4*)wp)[2];
    }
    const float bias = dtb[k * DI_ + d];

    const long l0 = (long)chunk * CL;
    const float* xsp = xs + (long)bk * L_ * DI_ + l0 * DI_ + d;
    const float* rbase = xdbl + (long)bk * L_ * C44 + l0 * C44;
    float* yp = outy + (long)bk * L_ * DI_ + l0 * DI_ + d;

    float s[16];
    if (chunk == 0) {
        #pragma unroll
        for (int n = 0; n < 16; ++n) s[n] = 0.f;
    } else {
        const float* cs = carryS + (long)(chunk - 1) * NSER + ((long)bk * DI_ + d) * 16;
        #pragma unroll
        for (int q = 0; q < 4; ++q) {
            float4 v = ((const float4*)cs)[q];
            s[q*4] = v.x; s[q*4+1] = v.y; s[q*4+2] = v.z; s[q*4+3] = v.w;
        }
    }

    for (int l = 0; l < CL; ++l) {
        const float* rb = rbase + (long)l * C44;
        float u = xsp[(long)l * DI_];
        float dl = fused_delta(rb, wt, bias);
        float B[16], Cc[16];
        *(float4*)&B[0]   = ((const float4*)rb)[3];
        *(float4*)&B[4]   = ((const float4*)rb)[4];
        *(float4*)&B[8]   = ((const float4*)rb)[5];
        *(float4*)&B[12]  = ((const float4*)rb)[6];
        *(float4*)&Cc[0]  = ((const float4*)rb)[7];
        *(float4*)&Cc[4]  = ((const float4*)rb)[8];
        *(float4*)&Cc[8]  = ((const float4*)rb)[9];
        *(float4*)&Cc[12] = ((const float4*)rb)[10];
        const float du = dl * u;
        float y = Dv * u;
        #pragma unroll
        for (int n = 0; n < 16; ++n) {
            s[n] = s[n] * __expf(dl * An[n]) + du * B[n];
            y += s[n] * Cc[n];
        }
        yp[(long)l * DI_] = y;
    }
}

// ---------------------------------------------------------------------------
// Combine 4 scan directions + LayerNorm(384) + SiLU(z) gate.
// ---------------------------------------------------------------------------
__global__ __launch_bounds__(384) void combine_ln(
    const float* __restrict__ outy, const float* __restrict__ xz,
    const float* __restrict__ g, const float* __restrict__ bta,
    float* __restrict__ yln)
{
    const int bl = blockIdx.x;
    const int b = bl / L_;
    const int l = bl % L_;
    const int h = l / W_;
    const int w = l % W_;
    const int d = threadIdx.x;

    const long base = (long)b * K_ * L_ * DI_;
    const int l1 = w * H_ + h;
    float v = outy[base + 0L * L_ * DI_ + (long)l            * DI_ + d]
            + outy[base + 2L * L_ * DI_ + (long)(L_ - 1 - l) * DI_ + d]
            + outy[base + 1L * L_ * DI_ + (long)l1           * DI_ + d]
            + outy[base + 3L * L_ * DI_ + (long)(L_ - 1 - l1)* DI_ + d];

    __shared__ float red[16];
    const int lane = d & 63, wid = d >> 6;

    float s = v;
    #pragma unroll
    for (int off = 32; off; off >>= 1) s += __shfl_down(s, off, 64);
    if (lane == 0) red[wid] = s;
    __syncthreads();
    if (d == 0) {
        float t = 0.f;
        for (int i = 0; i < 6; ++i) t += red[i];
        red[8] = t * (1.f / DI_);
    }
    __syncthreads();
    const float mu = red[8];
    float dv = v - mu;
    float s2 = dv * dv;
    #pragma unroll
    for (int off = 32; off; off >>= 1) s2 += __shfl_down(s2, off, 64);
    if (lane == 0) red[wid] = s2;
    __syncthreads();
    if (d == 0) {
        float t = 0.f;
        for (int i = 0; i < 6; ++i) t += red[i];
        red[9] = t * (1.f / DI_);
    }
    __syncthreads();
    const float var = red[9];

    float z = xz[(long)bl * (2 * DI_) + DI_ + d];
    float sz = z / (1.f + __expf(-z));
    float o = dv * rsqrtf(var + 1e-5f) * g[d] + bta[d];
    yln[(long)bl * DI_ + d] = o * sz;
}

// ---------------------------------------------------------------------------
extern "C" void kernel_launch(void* const* d_in, const int* in_sizes, int n_in,
                              void* d_out, int out_size, void* d_ws, size_t ws_size,
                              hipStream_t stream)
{
    const float* x    = (const float*)d_in[0];
    const float* xt   = (const float*)d_in[1];
    const float* ipw  = (const float*)d_in[2];
    const float* c2w  = (const float*)d_in[3];
    const float* c2b  = (const float*)d_in[4];
    const float* cxw  = (const float*)d_in[5];
    const float* cxb  = (const float*)d_in[6];
    const float* xpw  = (const float*)d_in[7];
    const float* dtw  = (const float*)d_in[8];
    const float* dtb  = (const float*)d_in[9];
    const float* alog = (const float*)d_in[10];
    const float* Dsp  = (const float*)d_in[11];
    const float* ng   = (const float*)d_in[12];
    const float* nb   = (const float*)d_in[13];
    const float* opw  = (const float*)d_in[14];
    float* out = (float*)d_out;

    const size_t M = (size_t)B_ * L_;          // 9216
    float* ws = (float*)d_ws;
    float* xz    = ws;                                   // [M,768]       28.3 MB
    float* xc    = xz    + M * (2 * DI_);                // [B,H,W,DI]    14.2 MB
    float* xtc   = xc    + M * DI_;                      // [B,H,W,DI]    14.2 MB
    float* xs    = xtc   + M * DI_;                      // [B,4,L,DI]    56.6 MB
    float* xdbl  = xs    + (size_t)B_ * K_ * L_ * DI_;   // [B,4,L,44]     6.5 MB
    float* carryS= xdbl  + (size_t)B_ * K_ * L_ * C44;   // [NC][NSER]    25.2 MB
    float* carryP= carryS + (size_t)NC * NSER;           // [NC][NSER]    25.2 MB
    float* outy  = carryP + (size_t)NC * NSER;           // [B,4,L,DI]    56.6 MB
    float* yln   = xc;                                   // reuse (xc dead after build_xs)

    dim3 blk(256);

    // K1: xz = x @ in_proj_w^T
    gemm_nt<0><<<dim3((int)(M / BM), (2 * DI_) / BN, 1), blk, 0, stream>>>(
        x, ipw, xz, nullptr, (int)M, 2 * DI_, DM_, DM_, DM_, 2 * DI_, 0, 0, 1, 0);

    // K2: convs + SiLU
    {
        int tot = 2 * B_ * H_ * W_ * DI_;
        conv_dw<<<(tot + 255) / 256, blk, 0, stream>>>(xz, xt, c2w, c2b, cxw, cxb, xc, xtc);
    }

    // K3: build xs
    {
        int tot = B_ * H_ * W_ * DI_;
        build_xs<<<(tot + 255) / 256, blk, 0, stream>>>(xc, xtc, xs);
    }

    // K4: x_dbl = xs @ xpw^T (batched over b,k)
    gemm_nt<0><<<dim3(L_ / BM, 1, B_ * K_), blk, 0, stream>>>(
        xs, xpw, xdbl, nullptr, L_, C44, DI_, DI_, DI_, C44,
        (long)L_ * DI_, (long)C44 * DI_, K_, (long)L_ * C44);

    // K6: chunked selective scan (3 passes, register-state, fused dt-proj)
    scan_p1<<<B_ * K_ * (NC - 1), 384, 0, stream>>>(
        xs, xdbl, alog, dtw, dtb, carryS, carryP);
    scan_p2<<<NSER / 256, blk, 0, stream>>>(carryS, carryP);
    scan_p3<<<B_ * K_ * NC, 384, 0, stream>>>(
        xs, xdbl, alog, dtw, dtb, Dsp, carryS, outy);

    // K7: combine + LayerNorm + SiLU gate
    combine_ln<<<(int)M, 384, 0, stream>>>(outy, xz, ng, nb, yln);

    // K8: out = yln @ out_proj_w^T
    gemm_nt<0><<<dim3((int)(M / BM), DM_ / BN, 1), blk, 0, stream>>>(
        yln, opw, out, nullptr, (int)M, DM_, DI_, DI_, DI_, DM_, 0, 0, 1, 0);
}

// Round 5
// 496.682 us; speedup vs baseline: 1.0920x; 1.0920x over previous
//
#include <hip/hip_runtime.h>
#include <math.h>

#define B_   4
#define H_   48
#define W_   48
#define DM_  192
#define DI_  384
#define L_   2304      // H_*W_
#define K_   4
#define DS_  16
#define DTR_ 12
#define C44  44        // DTR + 2*DS

// scan chunking
#define NC   64
#define CL   36                        // L_/NC
#define NSER (B_*K_*DI_*DS_)           // 98304 series (b,k,d,n)

// ---------------------------------------------------------------------------
// Generic batched NT GEMM: C[m,n] = sum_k A[m,k]*B[n,k]
// ---------------------------------------------------------------------------
#define BM 64
#define BN 64
#define BKT 16

template<int EPI>
__global__ __launch_bounds__(256) void gemm_nt(
    const float* __restrict__ Ag, const float* __restrict__ Bg,
    float* __restrict__ Cg, const float* __restrict__ biasg,
    int M, int N, int Kd, int lda, int ldb, int ldc,
    long sA, long sB, int bmod, long sC)
{
    const int batch = blockIdx.z;
    const float* A = Ag + (long)batch * sA;
    const float* Bm = Bg + (long)(batch % bmod) * sB;
    float* C = Cg + (long)batch * sC;
    const float* bias = (EPI == 1) ? (biasg + (long)(batch % bmod) * N) : nullptr;

    __shared__ __align__(16) float As[BKT][BM + 4];
    __shared__ __align__(16) float Bs[BKT][BN + 4];

    const int tid = threadIdx.x;
    const int tx = tid & 15;
    const int ty = tid >> 4;
    const int row0 = blockIdx.x * BM;
    const int col0 = blockIdx.y * BN;

    const int kc = tid & (BKT - 1);
    const int rr = tid >> 4;

    float acc[4][4] = {};

    for (int k0 = 0; k0 < Kd; k0 += BKT) {
        #pragma unroll
        for (int p = 0; p < 4; ++p) {
            int r = rr + p * 16;
            int gk = k0 + kc;
            int gr = row0 + r;
            float va = 0.f;
            if (gr < M && gk < Kd) va = A[(long)gr * lda + gk];
            As[kc][r] = va;
            int gc = col0 + r;
            float vb = 0.f;
            if (gc < N && gk < Kd) vb = Bm[(long)gc * ldb + gk];
            Bs[kc][r] = vb;
        }
        __syncthreads();
        #pragma unroll
        for (int kk = 0; kk < BKT; ++kk) {
            float4 a4 = *(const float4*)&As[kk][ty * 4];
            float4 b4 = *(const float4*)&Bs[kk][tx * 4];
            float a[4] = {a4.x, a4.y, a4.z, a4.w};
            float b[4] = {b4.x, b4.y, b4.z, b4.w};
            #pragma unroll
            for (int i = 0; i < 4; ++i)
                #pragma unroll
                for (int j = 0; j < 4; ++j)
                    acc[i][j] += a[i] * b[j];
        }
        __syncthreads();
    }

    #pragma unroll
    for (int i = 0; i < 4; ++i) {
        int gr = row0 + ty * 4 + i;
        if (gr >= M) continue;
        #pragma unroll
        for (int j = 0; j < 4; ++j) {
            int gc = col0 + tx * 4 + j;
            if (gc >= N) continue;
            float v = acc[i][j];
            if (EPI == 1) {
                v += bias[gc];
                v = (v > 20.f) ? v : __logf(1.f + __expf(v));
            }
            C[(long)gr * ldc + gc] = v;
        }
    }
}

// ---------------------------------------------------------------------------
// Depthwise/grouped 3x3 convs + bias + SiLU.
// ---------------------------------------------------------------------------
__global__ __launch_bounds__(256) void conv_dw(
    const float* __restrict__ xz, const float* __restrict__ xt,
    const float* __restrict__ w1, const float* __restrict__ b1,
    const float* __restrict__ w2, const float* __restrict__ b2,
    float* __restrict__ xc, float* __restrict__ xtc)
{
    const int total = B_ * H_ * W_ * DI_;
    int idx = blockIdx.x * blockDim.x + threadIdx.x;
    if (idx >= 2 * total) return;
    const bool second = idx >= total;
    int i = second ? idx - total : idx;
    const int c = i % DI_;
    int rest = i / DI_;
    const int w = rest % W_; rest /= W_;
    const int h = rest % H_;
    const int b = rest / H_;

    float acc;
    if (!second) {
        acc = b1[c];
        const float* wp = w1 + c * 9;
        #pragma unroll
        for (int dh = 0; dh < 3; ++dh) {
            int hh = h + dh - 1;
            if (hh < 0 || hh >= H_) continue;
            #pragma unroll
            for (int dw = 0; dw < 3; ++dw) {
                int ww = w + dw - 1;
                if (ww < 0 || ww >= W_) continue;
                acc += xz[((long)((b * H_ + hh) * W_ + ww)) * (2 * DI_) + c] * wp[dh * 3 + dw];
            }
        }
    } else {
        acc = b2[c];
        const int ci = c >> 1;
        const float* wp = w2 + c * 9;
        #pragma unroll
        for (int dh = 0; dh < 3; ++dh) {
            int hh = h + dh - 1;
            if (hh < 0 || hh >= H_) continue;
            #pragma unroll
            for (int dw = 0; dw < 3; ++dw) {
                int ww = w + dw - 1;
                if (ww < 0 || ww >= W_) continue;
                acc += xt[((long)((b * H_ + hh) * W_ + ww)) * DM_ + ci] * wp[dh * 3 + dw];
            }
        }
    }
    float v = acc / (1.f + __expf(-acc));   // SiLU
    (second ? xtc : xc)[i] = v;
}

// ---------------------------------------------------------------------------
// Build xs[B,4,L,DI]
// ---------------------------------------------------------------------------
__global__ __launch_bounds__(256) void build_xs(
    const float* __restrict__ xc, const float* __restrict__ xtc,
    float* __restrict__ xs)
{
    const int total = B_ * H_ * W_ * DI_;
    int idx = blockIdx.x * blockDim.x + threadIdx.x;
    if (idx >= total) return;
    const int d = idx % DI_;
    int rest = idx / DI_;
    const int w = rest % W_; rest /= W_;
    const int h = rest % H_;
    const int b = rest / H_;

    float a, bb, ir, ic;
    if ((h & 1) == 0) {
        a  = xc[((long)((b * H_ + h)     * W_ + w)) * DI_ + d];
        bb = xc[((long)((b * H_ + h + 1) * W_ + w)) * DI_ + d];
    } else {
        a  = xtc[((long)((b * H_ + h - 1) * W_ + w)) * DI_ + d];
        bb = xtc[((long)((b * H_ + h)     * W_ + w)) * DI_ + d];
    }
    ir = 0.5f * (a + bb) + fmaxf(a, bb);
    if ((w & 1) == 0) {
        a  = xc[((long)((b * H_ + h) * W_ + w))     * DI_ + d];
        bb = xc[((long)((b * H_ + h) * W_ + w + 1)) * DI_ + d];
    } else {
        a  = xtc[((long)((b * H_ + h) * W_ + w - 1)) * DI_ + d];
        bb = xtc[((long)((b * H_ + h) * W_ + w))     * DI_ + d];
    }
    ic = 0.5f * (a + bb) + fmaxf(a, bb);

    long base = (long)b * K_ * L_ * DI_;
    xs[base + 0L * L_ * DI_ + (long)(w * H_ + h)            * DI_ + d] = ir;
    xs[base + 1L * L_ * DI_ + (long)(w * H_ + (H_ - 1 - h)) * DI_ + d] = ir;
    xs[base + 2L * L_ * DI_ + (long)(h * W_ + w)            * DI_ + d] = ic;
    xs[base + 3L * L_ * DI_ + (long)(h * W_ + (W_ - 1 - w)) * DI_ + d] = ic;
}

// ---------------------------------------------------------------------------
// Chunked selective scan, 3 passes, dt-proj fused, xdbl chunk staged in LDS.
// One thread per d-channel, 16 states in VGPRs. Block = 384 thr = (b,k,chunk).
// Carry layout: [chunk][(bk*DI+d)*16+n].
// ---------------------------------------------------------------------------
__device__ __forceinline__ float fused_delta(
    const float* __restrict__ rb, const float wt[12], float bias)
{
    float4 t0 = ((const float4*)rb)[0];
    float4 t1 = ((const float4*)rb)[1];
    float4 t2 = ((const float4*)rb)[2];
    float v = bias;
    v += t0.x * wt[0] + t0.y * wt[1] + t0.z * wt[2] + t0.w * wt[3];
    v += t1.x * wt[4] + t1.y * wt[5] + t1.z * wt[6] + t1.w * wt[7];
    v += t2.x * wt[8] + t2.y * wt[9] + t2.z * wt[10] + t2.w * wt[11];
    return (v > 20.f) ? v : __logf(1.f + __expf(v));
}

__global__ __launch_bounds__(384) void scan_p1(
    const float* __restrict__ xs, const float* __restrict__ xdbl,
    const float* __restrict__ A_logs, const float* __restrict__ dtw,
    const float* __restrict__ dtb,
    float* __restrict__ carryS, float* __restrict__ carryP)
{
    __shared__ __align__(16) float sh[CL * C44];   // 6336 B
    const int chunk = blockIdx.x % (NC - 1);
    const int bk = blockIdx.x / (NC - 1);
    const int k = bk % K_;
    const int d = threadIdx.x;

    // cooperative stage of this chunk's xdbl rows (dt|B cols used)
    {
        const float* src = xdbl + (long)bk * L_ * C44 + (long)chunk * CL * C44;
        for (int i = threadIdx.x; i < CL * C44; i += 384) sh[i] = src[i];
    }

    float An[16];
    #pragma unroll
    for (int n = 0; n < 16; ++n)
        An[n] = -__expf(A_logs[(long)(k * DI_ + d) * DS_ + n]);

    float wt[12];
    {
        const float* wp = dtw + ((long)k * DI_ + d) * DTR_;
        *(float4*)&wt[0] = ((const float4*)wp)[0];
        *(float4*)&wt[4] = ((const float4*)wp)[1];
        *(float4*)&wt[8] = ((const float4*)wp)[2];
    }
    const float bias = dtb[k * DI_ + d];

    __syncthreads();

    const float* xsp = xs + (long)bk * L_ * DI_ + (long)chunk * CL * DI_ + d;

    float s[16];
    #pragma unroll
    for (int n = 0; n < 16; ++n) s[n] = 0.f;
    float sdl = 0.f;

    for (int l4 = 0; l4 < CL; l4 += 4) {
        float u4[4];
        #pragma unroll
        for (int j = 0; j < 4; ++j) u4[j] = xsp[(long)(l4 + j) * DI_];
        #pragma unroll
        for (int j = 0; j < 4; ++j) {
            const float* rb = sh + (l4 + j) * C44;
            float dl = fused_delta(rb, wt, bias);
            float B[16];
            *(float4*)&B[0]  = ((const float4*)rb)[3];
            *(float4*)&B[4]  = ((const float4*)rb)[4];
            *(float4*)&B[8]  = ((const float4*)rb)[5];
            *(float4*)&B[12] = ((const float4*)rb)[6];
            const float du = dl * u4[j];
            sdl += dl;
            #pragma unroll
            for (int n = 0; n < 16; ++n)
                s[n] = s[n] * __expf(dl * An[n]) + du * B[n];
        }
    }

    const long sidb = ((long)bk * DI_ + d) * 16;
    float* cs = carryS + (long)chunk * NSER + sidb;
    float* cpp = carryP + (long)chunk * NSER + sidb;
    #pragma unroll
    for (int q = 0; q < 4; ++q) {
        float4 v; v.x = s[q*4]; v.y = s[q*4+1]; v.z = s[q*4+2]; v.w = s[q*4+3];
        ((float4*)cs)[q] = v;
        float4 p;
        p.x = __expf(An[q*4+0] * sdl); p.y = __expf(An[q*4+1] * sdl);
        p.z = __expf(An[q*4+2] * sdl); p.w = __expf(An[q*4+3] * sdl);
        ((float4*)cpp)[q] = p;
    }
}

// sequential combine across chunks, in place: after this, carryS[c-1] holds
// the incoming state for chunk c (chunk 0 incoming = 0).
__global__ __launch_bounds__(256) void scan_p2(
    float* __restrict__ carryS, const float* __restrict__ carryP)
{
    const int sid = blockIdx.x * 256 + threadIdx.x;
    float s = 0.f;
    #pragma unroll
    for (int c = 1; c < NC; ++c) {
        float Sv = carryS[(long)(c - 1) * NSER + sid];
        float Pv = carryP[(long)(c - 1) * NSER + sid];
        s = Pv * s + Sv;
        carryS[(long)(c - 1) * NSER + sid] = s;
    }
}

__global__ __launch_bounds__(384) void scan_p3(
    const float* __restrict__ xs, const float* __restrict__ xdbl,
    const float* __restrict__ A_logs, const float* __restrict__ dtw,
    const float* __restrict__ dtb, const float* __restrict__ Ds,
    const float* __restrict__ carryS, float* __restrict__ outy)
{
    __shared__ __align__(16) float sh[CL * C44];   // 6336 B
    const int chunk = blockIdx.x % NC;
    const int bk = blockIdx.x / NC;
    const int k = bk % K_;
    const int d = threadIdx.x;

    {
        const float* src = xdbl + (long)bk * L_ * C44 + (long)chunk * CL * C44;
        for (int i = threadIdx.x; i < CL * C44; i += 384) sh[i] = src[i];
    }

    float An[16];
    #pragma unroll
    for (int n = 0; n < 16; ++n)
        An[n] = -__expf(A_logs[(long)(k * DI_ + d) * DS_ + n]);
    const float Dv = Ds[k * DI_ + d];

    float wt[12];
    {
        const float* wp = dtw + ((long)k * DI_ + d) * DTR_;
        *(float4*)&wt[0] = ((const float4*)wp)[0];
        *(float4*)&wt[4] = ((const float4*)wp)[1];
        *(float4*)&wt[8] = ((const float4*)wp)[2];
    }
    const float bias = dtb[k * DI_ + d];

    float s[16];
    if (chunk == 0) {
        #pragma unroll
        for (int n = 0; n < 16; ++n) s[n] = 0.f;
    } else {
        const float* cs = carryS + (long)(chunk - 1) * NSER + ((long)bk * DI_ + d) * 16;
        #pragma unroll
        for (int q = 0; q < 4; ++q) {
            float4 v = ((const float4*)cs)[q];
            s[q*4] = v.x; s[q*4+1] = v.y; s[q*4+2] = v.z; s[q*4+3] = v.w;
        }
    }

    __syncthreads();

    const float* xsp = xs + (long)bk * L_ * DI_ + (long)chunk * CL * DI_ + d;
    float* yp = outy + (long)bk * L_ * DI_ + (long)chunk * CL * DI_ + d;

    for (int l4 = 0; l4 < CL; l4 += 4) {
        float u4[4];
        #pragma unroll
        for (int j = 0; j < 4; ++j) u4[j] = xsp[(long)(l4 + j) * DI_];
        #pragma unroll
        for (int j = 0; j < 4; ++j) {
            const float* rb = sh + (l4 + j) * C44;
            float dl = fused_delta(rb, wt, bias);
            float B[16], Cc[16];
            *(float4*)&B[0]   = ((const float4*)rb)[3];
            *(float4*)&B[4]   = ((const float4*)rb)[4];
            *(float4*)&B[8]   = ((const float4*)rb)[5];
            *(float4*)&B[12]  = ((const float4*)rb)[6];
            *(float4*)&Cc[0]  = ((const float4*)rb)[7];
            *(float4*)&Cc[4]  = ((const float4*)rb)[8];
            *(float4*)&Cc[8]  = ((const float4*)rb)[9];
            *(float4*)&Cc[12] = ((const float4*)rb)[10];
            const float du = dl * u4[j];
            float y = Dv * u4[j];
            #pragma unroll
            for (int n = 0; n < 16; ++n) {
                s[n] = s[n] * __expf(dl * An[n]) + du * B[n];
                y += s[n] * Cc[n];
            }
            yp[(long)(l4 + j) * DI_] = y;
        }
    }
}

// ---------------------------------------------------------------------------
// Combine 4 scan directions + LayerNorm(384) + SiLU(z) gate.
// ---------------------------------------------------------------------------
__global__ __launch_bounds__(384) void combine_ln(
    const float* __restrict__ outy, const float* __restrict__ xz,
    const float* __restrict__ g, const float* __restrict__ bta,
    float* __restrict__ yln)
{
    const int bl = blockIdx.x;
    const int b = bl / L_;
    const int l = bl % L_;
    const int h = l / W_;
    const int w = l % W_;
    const int d = threadIdx.x;

    const long base = (long)b * K_ * L_ * DI_;
    const int l1 = w * H_ + h;
    float v = outy[base + 0L * L_ * DI_ + (long)l            * DI_ + d]
            + outy[base + 2L * L_ * DI_ + (long)(L_ - 1 - l) * DI_ + d]
            + outy[base + 1L * L_ * DI_ + (long)l1           * DI_ + d]
            + outy[base + 3L * L_ * DI_ + (long)(L_ - 1 - l1)* DI_ + d];

    __shared__ float red[16];
    const int lane = d & 63, wid = d >> 6;

    float s = v;
    #pragma unroll
    for (int off = 32; off; off >>= 1) s += __shfl_down(s, off, 64);
    if (lane == 0) red[wid] = s;
    __syncthreads();
    if (d == 0) {
        float t = 0.f;
        for (int i = 0; i < 6; ++i) t += red[i];
        red[8] = t * (1.f / DI_);
    }
    __syncthreads();
    const float mu = red[8];
    float dv = v - mu;
    float s2 = dv * dv;
    #pragma unroll
    for (int off = 32; off; off >>= 1) s2 += __shfl_down(s2, off, 64);
    if (lane == 0) red[wid] = s2;
    __syncthreads();
    if (d == 0) {
        float t = 0.f;
        for (int i = 0; i < 6; ++i) t += red[i];
        red[9] = t * (1.f / DI_);
    }
    __syncthreads();
    const float var = red[9];

    float z = xz[(long)bl * (2 * DI_) + DI_ + d];
    float sz = z / (1.f + __expf(-z));
    float o = dv * rsqrtf(var + 1e-5f) * g[d] + bta[d];
    yln[(long)bl * DI_ + d] = o * sz;
}

// ---------------------------------------------------------------------------
extern "C" void kernel_launch(void* const* d_in, const int* in_sizes, int n_in,
                              void* d_out, int out_size, void* d_ws, size_t ws_size,
                              hipStream_t stream)
{
    const float* x    = (const float*)d_in[0];
    const float* xt   = (const float*)d_in[1];
    const float* ipw  = (const float*)d_in[2];
    const float* c2w  = (const float*)d_in[3];
    const float* c2b  = (const float*)d_in[4];
    const float* cxw  = (const float*)d_in[5];
    const float* cxb  = (const float*)d_in[6];
    const float* xpw  = (const float*)d_in[7];
    const float* dtw  = (const float*)d_in[8];
    const float* dtb  = (const float*)d_in[9];
    const float* alog = (const float*)d_in[10];
    const float* Dsp  = (const float*)d_in[11];
    const float* ng   = (const float*)d_in[12];
    const float* nb   = (const float*)d_in[13];
    const float* opw  = (const float*)d_in[14];
    float* out = (float*)d_out;

    const size_t M = (size_t)B_ * L_;          // 9216
    float* ws = (float*)d_ws;
    float* xz    = ws;                                   // [M,768]       28.3 MB
    float* xc    = xz    + M * (2 * DI_);                // [B,H,W,DI]    14.2 MB
    float* xtc   = xc    + M * DI_;                      // [B,H,W,DI]    14.2 MB
    float* xs    = xtc   + M * DI_;                      // [B,4,L,DI]    56.6 MB
    float* xdbl  = xs    + (size_t)B_ * K_ * L_ * DI_;   // [B,4,L,44]     6.5 MB
    float* carryS= xdbl  + (size_t)B_ * K_ * L_ * C44;   // [NC][NSER]    25.2 MB
    float* carryP= carryS + (size_t)NC * NSER;           // [NC][NSER]    25.2 MB
    float* outy  = carryP + (size_t)NC * NSER;           // [B,4,L,DI]    56.6 MB
    float* yln   = xc;                                   // reuse (xc dead after build_xs)

    dim3 blk(256);

    // K1: xz = x @ in_proj_w^T
    gemm_nt<0><<<dim3((int)(M / BM), (2 * DI_) / BN, 1), blk, 0, stream>>>(
        x, ipw, xz, nullptr, (int)M, 2 * DI_, DM_, DM_, DM_, 2 * DI_, 0, 0, 1, 0);

    // K2: convs + SiLU
    {
        int tot = 2 * B_ * H_ * W_ * DI_;
        conv_dw<<<(tot + 255) / 256, blk, 0, stream>>>(xz, xt, c2w, c2b, cxw, cxb, xc, xtc);
    }

    // K3: build xs
    {
        int tot = B_ * H_ * W_ * DI_;
        build_xs<<<(tot + 255) / 256, blk, 0, stream>>>(xc, xtc, xs);
    }

    // K4: x_dbl = xs @ xpw^T (batched over b,k)
    gemm_nt<0><<<dim3(L_ / BM, 1, B_ * K_), blk, 0, stream>>>(
        xs, xpw, xdbl, nullptr, L_, C44, DI_, DI_, DI_, C44,
        (long)L_ * DI_, (long)C44 * DI_, K_, (long)L_ * C44);

    // K6: chunked selective scan (3 passes, register-state, fused dt-proj,
    // LDS-staged xdbl)
    scan_p1<<<B_ * K_ * (NC - 1), 384, 0, stream>>>(
        xs, xdbl, alog, dtw, dtb, carryS, carryP);
    scan_p2<<<NSER / 256, blk, 0, stream>>>(carryS, carryP);
    scan_p3<<<B_ * K_ * NC, 384, 0, stream>>>(
        xs, xdbl, alog, dtw, dtb, Dsp, carryS, outy);

    // K7: combine + LayerNorm + SiLU gate
    combine_ln<<<(int)M, 384, 0, stream>>>(outy, xz, ng, nb, yln);

    // K8: out = yln @ out_proj_w^T
    gemm_nt<0><<<dim3((int)(M / BM), DM_ / BN, 1), blk, 0, stream>>>(
        yln, opw, out, nullptr, (int)M, DM_, DI_, DI_, DI_, DM_, 0, 0, 1, 0);
}